// Round 12
// baseline (217.177 us; speedup 1.0000x reference)
//
#include <hip/hip_runtime.h>
#include <math.h>

#define N_VOX 32768
#define N_EMB 8192
#define DIM 64
#define NCHUNK 8
#define CODES_PER_CHUNK (N_EMB / NCHUNK)       // 1024
#define TILES_PER_CHUNK (CODES_PER_CHUNK / 32) // 32
#define NTILES (N_EMB / 32)                    // 256
#define TILE_BYTES 8192                        // bh[4x1KB] | bl[4x1KB]
#define CHUNK_BYTES (TILES_PER_CHUNK * TILE_BYTES)

typedef _Float16 half8 __attribute__((ext_vector_type(8)));
typedef float floatx4 __attribute__((ext_vector_type(4)));

#define FP16_MIN_NORMAL 6.1035156e-5f
#define LO_SCALE 2048.0f

// -------- kernel A: fused esq + B-fragment stream build (validated) ----------
// 256 thr/tile (thread = one (o,lane) slice). UNCHANGED layout:
// element (code n, k) lives at tile byte 512*(k>>3) + 16*n (+4096 for bl).
// c0arr[code] = -1024*esq. Block 0 also zeroes the finalize sync counter
// (stream-ordered before finalize).
__global__ __launch_bounds__(256) void cbprep_kernel(const float* __restrict__ cb,
                                                     char* __restrict__ stream,
                                                     float* __restrict__ c0arr,
                                                     int* __restrict__ counter) {
    __shared__ float red[256];
    int tid  = threadIdx.x;                      // 0..255
    int l    = tid & 63;
    int o    = tid >> 6;                         // K-chunk 0..3
    int m    = l & 31;
    int tile = blockIdx.x;                       // 0..255
    char* tbase = stream + (size_t)tile * TILE_BYTES;
    int code = tile * 32 + m;
    int kg   = l >> 5;

    if (tile == 0 && tid == 0) *counter = 0;     // reset finalize sync

    const float* p = cb + (size_t)code * DIM + o * 16 + kg * 8;
    float ss = 0.f;
    half8 h, lo;
    #pragma unroll
    for (int j = 0; j < 8; ++j) {
        float x = p[j];
        ss = fmaf(x, x, ss);
        _Float16 hi = (_Float16)x;
        float hf = (float)hi;
        if (fabsf(hf) < FP16_MIN_NORMAL) { hi = (_Float16)0.f; hf = 0.f; }
        h[j]  = hi;
        lo[j] = (_Float16)((x - hf) * LO_SCALE);
    }
    *(half8*)(tbase +        o * 1024 + l * 16) = h;
    *(half8*)(tbase + 4096 + o * 1024 + l * 16) = lo;

    red[tid] = ss;
    __syncthreads();
    if (tid < 32) {                              // tid == m here
        float s = 0.f;
        #pragma unroll
        for (int q = 0; q < 8; ++q) s += red[tid + q * 32];
        c0arr[tile * 32 + tid] = -1024.0f * s;
    }
}

// -------- kernel B: MFMA argmin scan — R7 EXACT (best verified: 99.8µs) ------
// 8 waves/512thr, 32 rows/wave, 4 LDS buffers, counted-vmcnt 3-ahead, c0 in
// LDS; per-tile MFMA = 24x 16x16x32 forming 4 INDEPENDENT 6-deep chains
// (rowgroup r x colgroup c) — the R7 ILP win. 64 VGPR, 3 waves/SIMD.
// After R8-R11: reg-dbuf/stagger/no-LDS all lose to the register envelope;
// this structure is the verified optimum. DO NOT perturb the K-loop.
// Mappings (guide m89/m121): A/B idx=l&15, k=(l>>4)*8+j; C/D col=l&15,
// row=4*(l>>4)+reg. acc = 2048*(dot - esq/2) = c0 + zhs*bh + zl*bh + zh*bl.
// Maximize, tie -> lower within-chunk id (order-independent tournament).
__global__ __launch_bounds__(512) void scan_kernel(const float* __restrict__ z,
                                                   const char* __restrict__ stream,
                                                   const float* __restrict__ c0arr,
                                                   float* __restrict__ cand_val,
                                                   int* __restrict__ cand_idx) {
    __shared__ __align__(16) char lds[4 * TILE_BYTES + CODES_PER_CHUNK * 4];
    float* c0_lds = (float*)(lds + 4 * TILE_BYTES);
    int tid   = threadIdx.x;
    int l     = tid & 63;
    int w     = tid >> 6;                        // wave 0..7
    int chunk = blockIdx.x & (NCHUNK - 1);
    int rg    = blockIdx.x >> 3;                 // 0..127, 256 rows per block
    int lr    = l & 15;                          // A row / B col within group
    int lq    = l >> 4;                          // quarter: k-octet / C row-quad
    int rowBase = rg * 256 + w * 32;             // wave's 32 rows

    // A fragments per (rowgroup r, khalf h): zh, zl = 2048*res, zhs = 2048*zh
    half8 zh[2][2], zl[2][2], zhs[2][2];
    #pragma unroll
    for (int r = 0; r < 2; ++r) {
        #pragma unroll
        for (int h = 0; h < 2; ++h) {
            const float* p = z + (size_t)(rowBase + r * 16 + lr) * DIM + h * 32 + lq * 8;
            #pragma unroll
            for (int j = 0; j < 8; ++j) {
                float x = p[j];
                _Float16 hi = (_Float16)x;
                float hf = (float)hi;
                if (fabsf(hf) < FP16_MIN_NORMAL) { hi = (_Float16)0.f; hf = 0.f; }
                zh[r][h][j] = hi;
                zl[r][h][j] = (_Float16)((x - hf) * LO_SCALE);
            }
            zhs[r][h] = zh[r][h] * (_Float16)2048.0f;
        }
    }

    const char*  sbase = stream + (size_t)chunk * CHUNK_BYTES;
    const float* c0p   = c0arr + chunk * CODES_PER_CHUNK;

    // best/bt position p = r*8 + c*4 + i  (row = rowBase+r*16+4*lq+i,
    // col-in-tile = c*16+lr)
    float best[16];
    int   bt[16];
    #pragma unroll
    for (int i = 0; i < 16; ++i) { best[i] = -3.4e38f; bt[i] = 0; }

    // stage one 8KB tile: wave w issues seg w (1KB, lane l -> +l*16)
#define STAGE(gt, lb)                                                              \
    do {                                                                           \
        const char* _g = (gt) + w * 1024 + l * 16;                                 \
        char*       _d = (lb) + w * 1024 + l * 16;                                 \
        __builtin_amdgcn_global_load_lds(                                          \
            (const __attribute__((address_space(1))) void*)_g,                     \
            (__attribute__((address_space(3))) void*)_d, 16, 0, 0);                \
    } while (0)

    // prologue: stage tiles 0..2 into bufs 0..2, fill c0 LDS, full drain once
    STAGE(sbase,                          lds);
    STAGE(sbase + (size_t)TILE_BYTES,     lds + TILE_BYTES);
    STAGE(sbase + 2 * (size_t)TILE_BYTES, lds + 2 * TILE_BYTES);
    c0_lds[tid]       = c0p[tid];
    c0_lds[tid + 512] = c0p[tid + 512];
    __syncthreads();                             // drains vmcnt to 0 (once)

    for (int t = 0; t < TILES_PER_CHUNK; ++t) {
        if (t < TILES_PER_CHUNK - 2)
            asm volatile("s_waitcnt vmcnt(2)" ::: "memory");
        else if (t == TILES_PER_CHUNK - 2)
            asm volatile("s_waitcnt vmcnt(1)" ::: "memory");
        else
            asm volatile("s_waitcnt vmcnt(0)" ::: "memory");
        __builtin_amdgcn_s_barrier();            // all waves: stage t landed
        asm volatile("" ::: "memory");           // pin ds_reads below barrier

        if (t + 3 < TILES_PER_CHUNK)             // overwrites buf[(t-1)&3]
            STAGE(sbase + (size_t)(t + 3) * TILE_BYTES,
                  lds + ((t + 3) & 3) * TILE_BYTES);

        const char* lb = lds + (t & 3) * TILE_BYTES;
        const char* bp = lb + 512 * lq + 16 * lr;
        half8 bh00 = *(const half8*)(bp +    0);         // c=0, h=0
        half8 bh10 = *(const half8*)(bp +  256);         // c=1, h=0
        half8 bh01 = *(const half8*)(bp + 2048);         // c=0, h=1
        half8 bh11 = *(const half8*)(bp + 2304);         // c=1, h=1
        half8 bl00 = *(const half8*)(bp + 4096);
        half8 bl10 = *(const half8*)(bp + 4352);
        half8 bl01 = *(const half8*)(bp + 6144);
        half8 bl11 = *(const half8*)(bp + 6400);
        float c00 = c0_lds[t * 32 + lr];                 // colgroup 0
        float c01 = c0_lds[t * 32 + 16 + lr];            // colgroup 1

        floatx4 a00 = {c00, c00, c00, c00};              // [r=0][c=0]
        floatx4 a01 = {c01, c01, c01, c01};              // [r=0][c=1]
        floatx4 a10 = {c00, c00, c00, c00};              // [r=1][c=0]
        floatx4 a11 = {c01, c01, c01, c01};              // [r=1][c=1]

        // 4 independent 6-deep chains, interleaved (ILP=4)
        __builtin_amdgcn_s_setprio(1);
        a00 = __builtin_amdgcn_mfma_f32_16x16x32_f16(zhs[0][0], bh00, a00, 0, 0, 0);
        a01 = __builtin_amdgcn_mfma_f32_16x16x32_f16(zhs[0][0], bh10, a01, 0, 0, 0);
        a10 = __builtin_amdgcn_mfma_f32_16x16x32_f16(zhs[1][0], bh00, a10, 0, 0, 0);
        a11 = __builtin_amdgcn_mfma_f32_16x16x32_f16(zhs[1][0], bh10, a11, 0, 0, 0);
        a00 = __builtin_amdgcn_mfma_f32_16x16x32_f16(zl[0][0],  bh00, a00, 0, 0, 0);
        a01 = __builtin_amdgcn_mfma_f32_16x16x32_f16(zl[0][0],  bh10, a01, 0, 0, 0);
        a10 = __builtin_amdgcn_mfma_f32_16x16x32_f16(zl[1][0],  bh00, a10, 0, 0, 0);
        a11 = __builtin_amdgcn_mfma_f32_16x16x32_f16(zl[1][0],  bh10, a11, 0, 0, 0);
        a00 = __builtin_amdgcn_mfma_f32_16x16x32_f16(zh[0][0],  bl00, a00, 0, 0, 0);
        a01 = __builtin_amdgcn_mfma_f32_16x16x32_f16(zh[0][0],  bl10, a01, 0, 0, 0);
        a10 = __builtin_amdgcn_mfma_f32_16x16x32_f16(zh[1][0],  bl00, a10, 0, 0, 0);
        a11 = __builtin_amdgcn_mfma_f32_16x16x32_f16(zh[1][0],  bl10, a11, 0, 0, 0);
        a00 = __builtin_amdgcn_mfma_f32_16x16x32_f16(zhs[0][1], bh01, a00, 0, 0, 0);
        a01 = __builtin_amdgcn_mfma_f32_16x16x32_f16(zhs[0][1], bh11, a01, 0, 0, 0);
        a10 = __builtin_amdgcn_mfma_f32_16x16x32_f16(zhs[1][1], bh01, a10, 0, 0, 0);
        a11 = __builtin_amdgcn_mfma_f32_16x16x32_f16(zhs[1][1], bh11, a11, 0, 0, 0);
        a00 = __builtin_amdgcn_mfma_f32_16x16x32_f16(zl[0][1],  bh01, a00, 0, 0, 0);
        a01 = __builtin_amdgcn_mfma_f32_16x16x32_f16(zl[0][1],  bh11, a01, 0, 0, 0);
        a10 = __builtin_amdgcn_mfma_f32_16x16x32_f16(zl[1][1],  bh01, a10, 0, 0, 0);
        a11 = __builtin_amdgcn_mfma_f32_16x16x32_f16(zl[1][1],  bh11, a11, 0, 0, 0);
        a00 = __builtin_amdgcn_mfma_f32_16x16x32_f16(zh[0][1],  bl01, a00, 0, 0, 0);
        a01 = __builtin_amdgcn_mfma_f32_16x16x32_f16(zh[0][1],  bl11, a01, 0, 0, 0);
        a10 = __builtin_amdgcn_mfma_f32_16x16x32_f16(zh[1][1],  bl01, a10, 0, 0, 0);
        a11 = __builtin_amdgcn_mfma_f32_16x16x32_f16(zh[1][1],  bl11, a11, 0, 0, 0);
        __builtin_amdgcn_s_setprio(0);

        #pragma unroll
        for (int i = 0; i < 4; ++i) {
            if (a00[i] > best[ 0 + i]) { best[ 0 + i] = a00[i]; bt[ 0 + i] = t; }
            if (a01[i] > best[ 4 + i]) { best[ 4 + i] = a01[i]; bt[ 4 + i] = t; }
            if (a10[i] > best[ 8 + i]) { best[ 8 + i] = a10[i]; bt[ 8 + i] = t; }
            if (a11[i] > best[12 + i]) { best[12 + i] = a11[i]; bt[12 + i] = t; }
        }
    }
#undef STAGE

    // Epilogue: in-lane colgroup merge, then 4-step shuffle argmax over the
    // 16 cols (lane bits 0..3). Tie -> lower within-chunk id (tournament on
    // (v desc, id asc) — order-independent, same semantics as validated).
    #pragma unroll
    for (int r = 0; r < 2; ++r) {
        #pragma unroll
        for (int i = 0; i < 4; ++i) {
            float v0 = best[r * 8 + i];     int id0 = bt[r * 8 + i] * 32 + lr;
            float v1 = best[r * 8 + 4 + i]; int id1 = bt[r * 8 + 4 + i] * 32 + 16 + lr;
            float v = v0; int id = id0;
            if (v1 > v || (v1 == v && id1 < id)) { v = v1; id = id1; }
            #pragma unroll
            for (int off = 1; off < 16; off <<= 1) {
                float ov = __shfl_xor(v, off, 64);
                int   oi = __shfl_xor(id, off, 64);
                if (ov > v || (ov == v && oi < id)) { v = ov; id = oi; }
            }
            if (lr == 0) {
                int row = rowBase + r * 16 + 4 * lq + i;
                cand_val[chunk * N_VOX + row] = v;
                cand_idx[chunk * N_VOX + row] = chunk * CODES_PER_CHUNK + id;
            }
        }
    }
}

// -------- kernel C: pick + gather + partial, FUSED loss (last-block) ---------
// Same validated finalize logic; after writing partials, each block bumps a
// device-scope counter; the LAST block (1023) re-runs loss_kernel's exact
// deterministic 1024->1 tree (bit-identical result) — saves one launch+gap.
__global__ __launch_bounds__(256) void finalize_kernel(const float* __restrict__ z,
                                                       const float* __restrict__ cb,
                                                       const float* __restrict__ cand_val,
                                                       const int* __restrict__ cand_idx,
                                                       float* __restrict__ out,
                                                       float* __restrict__ partials,
                                                       int* __restrict__ counter) {
    int g    = blockIdx.x * 256 + threadIdx.x;
    int row  = g >> 3;
    int c    = g & 7;                  // chunk / candidate 0..7

    float v  = cand_val[c * N_VOX + row];
    int   id = cand_idx[c * N_VOX + row];
    #pragma unroll
    for (int off = 1; off < 8; off <<= 1) {
        float ov = __shfl_xor(v, off, 8);
        int   oi = __shfl_xor(id, off, 8);
        if (ov > v || (ov == v && oi < id)) { v = ov; id = oi; }
    }
    // all 8 lanes hold the winning id for this row

    if (c == 0)
        out[(size_t)N_VOX * DIM + 2 + row] = (float)id;

    // cooperative gather+write: lane handles elements [c*8, c*8+8)
    const float4* zp = (const float4*)(z  + (size_t)row * DIM + c * 8);
    const float4* qp = (const float4*)(cb + (size_t)id  * DIM + c * 8);
    float4*       op = (float4*)(out + (size_t)row * DIM + c * 8);
    float ss = 0.f;
    #pragma unroll
    for (int d = 0; d < 2; ++d) {
        float4 zt = zp[d], qt = qp[d];
        float dx = qt.x - zt.x, dy = qt.y - zt.y;
        float dz = qt.z - zt.z, dw = qt.w - zt.w;
        float4 o;
        o.x = zt.x + dx; o.y = zt.y + dy;   // mirrors reference z + (q - z)
        o.z = zt.z + dz; o.w = zt.w + dw;
        op[d] = o;
        ss += dx*dx + dy*dy + dz*dz + dw*dw;
    }

    __shared__ float red[256];
    __shared__ int lastFlag;
    red[threadIdx.x] = ss;
    __syncthreads();
    #pragma unroll
    for (int s = 128; s > 0; s >>= 1) {
        if (threadIdx.x < s) red[threadIdx.x] += red[threadIdx.x + s];
        __syncthreads();
    }
    if (threadIdx.x == 0) {
        partials[blockIdx.x] = red[0];
        __threadfence();                         // partials visible device-wide
        int old = atomicAdd(counter, 1);         // device-scope by default
        lastFlag = (old == (N_VOX * 8 / 256) - 1);
    }
    __syncthreads();

    if (lastFlag) {                              // last block: fused loss
        __threadfence();                         // acquire all partials
        red[threadIdx.x] = (partials[threadIdx.x]       + partials[threadIdx.x + 256])
                         + (partials[threadIdx.x + 512] + partials[threadIdx.x + 768]);
        __syncthreads();
        #pragma unroll
        for (int st = 128; st > 0; st >>= 1) {
            if (threadIdx.x < st) red[threadIdx.x] += red[threadIdx.x + st];
            __syncthreads();
        }
        if (threadIdx.x == 0) {
            float mean = red[0] / (float)((size_t)N_VOX * DIM);
            out[(size_t)N_VOX * DIM + 0] = mean;
            out[(size_t)N_VOX * DIM + 1] = mean;
        }
    }
}

extern "C" void kernel_launch(void* const* d_in, const int* in_sizes, int n_in,
                              void* d_out, int out_size, void* d_ws, size_t ws_size,
                              hipStream_t stream) {
    const float* z  = (const float*)d_in[0];   // [32768, 64]
    const float* cb = (const float*)d_in[1];   // [8192, 64]
    float* out = (float*)d_out;

    // ws: stream [2MB] | c0arr [32KB] | cand_val [1MB] | cand_idx [1MB] |
    //     partials [4KB] | counter [4B]
    char*  bstream  = (char*)d_ws;
    float* c0arr    = (float*)(bstream + (size_t)NTILES * TILE_BYTES);
    float* cand_val = c0arr + N_EMB;
    int*   cand_idx = (int*)(cand_val + (size_t)NCHUNK * N_VOX);
    float* partials = (float*)(cand_idx + (size_t)NCHUNK * N_VOX);
    int*   counter  = (int*)(partials + 1024);

    cbprep_kernel  <<<dim3(NTILES), dim3(256), 0, stream>>>(cb, bstream, c0arr, counter);
    scan_kernel    <<<dim3((N_VOX / 256) * NCHUNK), dim3(512), 0, stream>>>(z, bstream, c0arr, cand_val, cand_idx);
    finalize_kernel<<<dim3(N_VOX * 8 / 256), dim3(256), 0, stream>>>(z, cb, cand_val, cand_idx, out, partials, counter);
}

// Round 13
// 155.037 us; speedup vs baseline: 1.4008x; 1.4008x over previous
//
#include <hip/hip_runtime.h>
#include <math.h>

#define N_VOX 32768
#define N_EMB 8192
#define DIM 64
#define NCHUNK 8
#define CODES_PER_CHUNK (N_EMB / NCHUNK)       // 1024
#define TILES_PER_CHUNK (CODES_PER_CHUNK / 32) // 32
#define NTILES (N_EMB / 32)                    // 256
#define TILE_BYTES 8192                        // bh[4x1KB] | bl[4x1KB]
#define CHUNK_BYTES (TILES_PER_CHUNK * TILE_BYTES)

typedef _Float16 half8 __attribute__((ext_vector_type(8)));
typedef float floatx4 __attribute__((ext_vector_type(4)));

#define FP16_MIN_NORMAL 6.1035156e-5f
#define LO_SCALE 2048.0f

// -------- kernel A: fused esq + B-fragment stream build (validated R9-R12) ---
// 256 thr/tile (thread = one (o,lane) slice). UNCHANGED layout:
// element (code n, k) lives at tile byte 512*(k>>3) + 16*n (+4096 for bl).
// c0arr[code] = -1024*esq.
__global__ __launch_bounds__(256) void cbprep_kernel(const float* __restrict__ cb,
                                                     char* __restrict__ stream,
                                                     float* __restrict__ c0arr) {
    __shared__ float red[256];
    int tid  = threadIdx.x;                      // 0..255
    int l    = tid & 63;
    int o    = tid >> 6;                         // K-chunk 0..3
    int m    = l & 31;
    int tile = blockIdx.x;                       // 0..255
    char* tbase = stream + (size_t)tile * TILE_BYTES;
    int code = tile * 32 + m;
    int kg   = l >> 5;

    const float* p = cb + (size_t)code * DIM + o * 16 + kg * 8;
    float ss = 0.f;
    half8 h, lo;
    #pragma unroll
    for (int j = 0; j < 8; ++j) {
        float x = p[j];
        ss = fmaf(x, x, ss);
        _Float16 hi = (_Float16)x;
        float hf = (float)hi;
        if (fabsf(hf) < FP16_MIN_NORMAL) { hi = (_Float16)0.f; hf = 0.f; }
        h[j]  = hi;
        lo[j] = (_Float16)((x - hf) * LO_SCALE);
    }
    *(half8*)(tbase +        o * 1024 + l * 16) = h;
    *(half8*)(tbase + 4096 + o * 1024 + l * 16) = lo;

    red[tid] = ss;
    __syncthreads();
    if (tid < 32) {                              // tid == m here
        float s = 0.f;
        #pragma unroll
        for (int q = 0; q < 8; ++q) s += red[tid + q * 32];
        c0arr[tile * 32 + tid] = -1024.0f * s;
    }
}

// -------- kernel B: MFMA argmin scan — 16x16x32 shape, 4 independent chains --
// R13 = R7 EXACT (verified 99.8µs, 64 VGPR, 3 waves/SIMD, occ 38.8%).
// NOTE: NO s_setprio here — setprio brackets cost +4 VGPR (64->68, seen in
// R9/R10/R11/R12) which crosses the 3->2 waves/SIMD boundary (-44µs). The
// 64-VGPR envelope IS the performance; do not perturb the K-loop.
// Structure: 8 waves/512thr, 32 rows/wave, 4 LDS buffers, counted-vmcnt
// 3-ahead, c0 in LDS; per-tile MFMA = 24x 16x16x32 forming 4 INDEPENDENT
// 6-deep chains (rowgroup r x colgroup c) — the R7 ILP win over 32x32x16.
// Mappings (guide m89/m121, dtype-independent): A/B idx = l&15,
// k = (l>>4)*8+j; C/D col = l&15, row = 4*(l>>4)+reg.
// B-frag (c,h) = one b128 at 512*(l>>4)+16*(l&15) + {0,256,2048,2304}[h,c]
// (+4096 for bl), from stored byte(n,k) = 512*(k>>3)+16*n.
// acc = 2048*(dot - esq/2) = c0 + zhs*bh + zl*bh + zh*bl.
// Maximize, tie -> lower within-chunk id (order-independent tournament).
__global__ __launch_bounds__(512) void scan_kernel(const float* __restrict__ z,
                                                   const char* __restrict__ stream,
                                                   const float* __restrict__ c0arr,
                                                   float* __restrict__ cand_val,
                                                   int* __restrict__ cand_idx) {
    __shared__ __align__(16) char lds[4 * TILE_BYTES + CODES_PER_CHUNK * 4];
    float* c0_lds = (float*)(lds + 4 * TILE_BYTES);
    int tid   = threadIdx.x;
    int l     = tid & 63;
    int w     = tid >> 6;                        // wave 0..7
    int chunk = blockIdx.x & (NCHUNK - 1);
    int rg    = blockIdx.x >> 3;                 // 0..127, 256 rows per block
    int lr    = l & 15;                          // A row / B col within group
    int lq    = l >> 4;                          // quarter: k-octet / C row-quad
    int rowBase = rg * 256 + w * 32;             // wave's 32 rows

    // A fragments per (rowgroup r, khalf h): zh, zl = 2048*res, zhs = 2048*zh
    half8 zh[2][2], zl[2][2], zhs[2][2];
    #pragma unroll
    for (int r = 0; r < 2; ++r) {
        #pragma unroll
        for (int h = 0; h < 2; ++h) {
            const float* p = z + (size_t)(rowBase + r * 16 + lr) * DIM + h * 32 + lq * 8;
            #pragma unroll
            for (int j = 0; j < 8; ++j) {
                float x = p[j];
                _Float16 hi = (_Float16)x;
                float hf = (float)hi;
                if (fabsf(hf) < FP16_MIN_NORMAL) { hi = (_Float16)0.f; hf = 0.f; }
                zh[r][h][j] = hi;
                zl[r][h][j] = (_Float16)((x - hf) * LO_SCALE);
            }
            zhs[r][h] = zh[r][h] * (_Float16)2048.0f;
        }
    }

    const char*  sbase = stream + (size_t)chunk * CHUNK_BYTES;
    const float* c0p   = c0arr + chunk * CODES_PER_CHUNK;

    // best/bt position p = r*8 + c*4 + i  (row = rowBase+r*16+4*lq+i,
    // col-in-tile = c*16+lr)
    float best[16];
    int   bt[16];
    #pragma unroll
    for (int i = 0; i < 16; ++i) { best[i] = -3.4e38f; bt[i] = 0; }

    // stage one 8KB tile: wave w issues seg w (1KB, lane l -> +l*16)
#define STAGE(gt, lb)                                                              \
    do {                                                                           \
        const char* _g = (gt) + w * 1024 + l * 16;                                 \
        char*       _d = (lb) + w * 1024 + l * 16;                                 \
        __builtin_amdgcn_global_load_lds(                                          \
            (const __attribute__((address_space(1))) void*)_g,                     \
            (__attribute__((address_space(3))) void*)_d, 16, 0, 0);                \
    } while (0)

    // prologue: stage tiles 0..2 into bufs 0..2, fill c0 LDS, full drain once
    STAGE(sbase,                          lds);
    STAGE(sbase + (size_t)TILE_BYTES,     lds + TILE_BYTES);
    STAGE(sbase + 2 * (size_t)TILE_BYTES, lds + 2 * TILE_BYTES);
    c0_lds[tid]       = c0p[tid];
    c0_lds[tid + 512] = c0p[tid + 512];
    __syncthreads();                             // drains vmcnt to 0 (once)

    for (int t = 0; t < TILES_PER_CHUNK; ++t) {
        if (t < TILES_PER_CHUNK - 2)
            asm volatile("s_waitcnt vmcnt(2)" ::: "memory");
        else if (t == TILES_PER_CHUNK - 2)
            asm volatile("s_waitcnt vmcnt(1)" ::: "memory");
        else
            asm volatile("s_waitcnt vmcnt(0)" ::: "memory");
        __builtin_amdgcn_s_barrier();            // all waves: stage t landed
        asm volatile("" ::: "memory");           // pin ds_reads below barrier

        if (t + 3 < TILES_PER_CHUNK)             // overwrites buf[(t-1)&3]
            STAGE(sbase + (size_t)(t + 3) * TILE_BYTES,
                  lds + ((t + 3) & 3) * TILE_BYTES);

        const char* lb = lds + (t & 3) * TILE_BYTES;
        const char* bp = lb + 512 * lq + 16 * lr;
        half8 bh00 = *(const half8*)(bp +    0);         // c=0, h=0
        half8 bh10 = *(const half8*)(bp +  256);         // c=1, h=0
        half8 bh01 = *(const half8*)(bp + 2048);         // c=0, h=1
        half8 bh11 = *(const half8*)(bp + 2304);         // c=1, h=1
        half8 bl00 = *(const half8*)(bp + 4096);
        half8 bl10 = *(const half8*)(bp + 4352);
        half8 bl01 = *(const half8*)(bp + 6144);
        half8 bl11 = *(const half8*)(bp + 6400);
        float c00 = c0_lds[t * 32 + lr];                 // colgroup 0
        float c01 = c0_lds[t * 32 + 16 + lr];            // colgroup 1

        floatx4 a00 = {c00, c00, c00, c00};              // [r=0][c=0]
        floatx4 a01 = {c01, c01, c01, c01};              // [r=0][c=1]
        floatx4 a10 = {c00, c00, c00, c00};              // [r=1][c=0]
        floatx4 a11 = {c01, c01, c01, c01};              // [r=1][c=1]

        // 4 independent 6-deep chains, interleaved (ILP=4)
        a00 = __builtin_amdgcn_mfma_f32_16x16x32_f16(zhs[0][0], bh00, a00, 0, 0, 0);
        a01 = __builtin_amdgcn_mfma_f32_16x16x32_f16(zhs[0][0], bh10, a01, 0, 0, 0);
        a10 = __builtin_amdgcn_mfma_f32_16x16x32_f16(zhs[1][0], bh00, a10, 0, 0, 0);
        a11 = __builtin_amdgcn_mfma_f32_16x16x32_f16(zhs[1][0], bh10, a11, 0, 0, 0);
        a00 = __builtin_amdgcn_mfma_f32_16x16x32_f16(zl[0][0],  bh00, a00, 0, 0, 0);
        a01 = __builtin_amdgcn_mfma_f32_16x16x32_f16(zl[0][0],  bh10, a01, 0, 0, 0);
        a10 = __builtin_amdgcn_mfma_f32_16x16x32_f16(zl[1][0],  bh00, a10, 0, 0, 0);
        a11 = __builtin_amdgcn_mfma_f32_16x16x32_f16(zl[1][0],  bh10, a11, 0, 0, 0);
        a00 = __builtin_amdgcn_mfma_f32_16x16x32_f16(zh[0][0],  bl00, a00, 0, 0, 0);
        a01 = __builtin_amdgcn_mfma_f32_16x16x32_f16(zh[0][0],  bl10, a01, 0, 0, 0);
        a10 = __builtin_amdgcn_mfma_f32_16x16x32_f16(zh[1][0],  bl00, a10, 0, 0, 0);
        a11 = __builtin_amdgcn_mfma_f32_16x16x32_f16(zh[1][0],  bl10, a11, 0, 0, 0);
        a00 = __builtin_amdgcn_mfma_f32_16x16x32_f16(zhs[0][1], bh01, a00, 0, 0, 0);
        a01 = __builtin_amdgcn_mfma_f32_16x16x32_f16(zhs[0][1], bh11, a01, 0, 0, 0);
        a10 = __builtin_amdgcn_mfma_f32_16x16x32_f16(zhs[1][1], bh01, a10, 0, 0, 0);
        a11 = __builtin_amdgcn_mfma_f32_16x16x32_f16(zhs[1][1], bh11, a11, 0, 0, 0);
        a00 = __builtin_amdgcn_mfma_f32_16x16x32_f16(zl[0][1],  bh01, a00, 0, 0, 0);
        a01 = __builtin_amdgcn_mfma_f32_16x16x32_f16(zl[0][1],  bh11, a01, 0, 0, 0);
        a10 = __builtin_amdgcn_mfma_f32_16x16x32_f16(zl[1][1],  bh01, a10, 0, 0, 0);
        a11 = __builtin_amdgcn_mfma_f32_16x16x32_f16(zl[1][1],  bh11, a11, 0, 0, 0);
        a00 = __builtin_amdgcn_mfma_f32_16x16x32_f16(zh[0][1],  bl01, a00, 0, 0, 0);
        a01 = __builtin_amdgcn_mfma_f32_16x16x32_f16(zh[0][1],  bl11, a01, 0, 0, 0);
        a10 = __builtin_amdgcn_mfma_f32_16x16x32_f16(zh[1][1],  bl01, a10, 0, 0, 0);
        a11 = __builtin_amdgcn_mfma_f32_16x16x32_f16(zh[1][1],  bl11, a11, 0, 0, 0);

        #pragma unroll
        for (int i = 0; i < 4; ++i) {
            if (a00[i] > best[ 0 + i]) { best[ 0 + i] = a00[i]; bt[ 0 + i] = t; }
            if (a01[i] > best[ 4 + i]) { best[ 4 + i] = a01[i]; bt[ 4 + i] = t; }
            if (a10[i] > best[ 8 + i]) { best[ 8 + i] = a10[i]; bt[ 8 + i] = t; }
            if (a11[i] > best[12 + i]) { best[12 + i] = a11[i]; bt[12 + i] = t; }
        }
    }
#undef STAGE

    // Epilogue: in-lane colgroup merge, then 4-step shuffle argmax over the
    // 16 cols (lane bits 0..3). Tie -> lower within-chunk id (tournament on
    // (v desc, id asc) — order-independent, same semantics as validated).
    #pragma unroll
    for (int r = 0; r < 2; ++r) {
        #pragma unroll
        for (int i = 0; i < 4; ++i) {
            float v0 = best[r * 8 + i];     int id0 = bt[r * 8 + i] * 32 + lr;
            float v1 = best[r * 8 + 4 + i]; int id1 = bt[r * 8 + 4 + i] * 32 + 16 + lr;
            float v = v0; int id = id0;
            if (v1 > v || (v1 == v && id1 < id)) { v = v1; id = id1; }
            #pragma unroll
            for (int off = 1; off < 16; off <<= 1) {
                float ov = __shfl_xor(v, off, 64);
                int   oi = __shfl_xor(id, off, 64);
                if (ov > v || (ov == v && oi < id)) { v = ov; id = oi; }
            }
            if (lr == 0) {
                int row = rowBase + r * 16 + 4 * lq + i;
                cand_val[chunk * N_VOX + row] = v;
                cand_idx[chunk * N_VOX + row] = chunk * CODES_PER_CHUNK + id;
            }
        }
    }
}

// -------- kernel C: pick max stored score + gather (no re-score) -------------
// 8 lanes per row: lane c reads chunk c's (val, idx); width-8 shuffle argmax
// (tie -> lower id) — identical ordering semantics to scan's within-chunk
// reduce, so cross-chunk pick is consistent with the validated pipeline.
__global__ __launch_bounds__(256) void finalize_kernel(const float* __restrict__ z,
                                                       const float* __restrict__ cb,
                                                       const float* __restrict__ cand_val,
                                                       const int* __restrict__ cand_idx,
                                                       float* __restrict__ out,
                                                       float* __restrict__ partials) {
    int g    = blockIdx.x * 256 + threadIdx.x;
    int row  = g >> 3;
    int c    = g & 7;                  // chunk / candidate 0..7

    float v  = cand_val[c * N_VOX + row];
    int   id = cand_idx[c * N_VOX + row];
    #pragma unroll
    for (int off = 1; off < 8; off <<= 1) {
        float ov = __shfl_xor(v, off, 8);
        int   oi = __shfl_xor(id, off, 8);
        if (ov > v || (ov == v && oi < id)) { v = ov; id = oi; }
    }
    // all 8 lanes hold the winning id for this row

    if (c == 0)
        out[(size_t)N_VOX * DIM + 2 + row] = (float)id;

    // cooperative gather+write: lane handles elements [c*8, c*8+8)
    const float4* zp = (const float4*)(z  + (size_t)row * DIM + c * 8);
    const float4* qp = (const float4*)(cb + (size_t)id  * DIM + c * 8);
    float4*       op = (float4*)(out + (size_t)row * DIM + c * 8);
    float ss = 0.f;
    #pragma unroll
    for (int d = 0; d < 2; ++d) {
        float4 zt = zp[d], qt = qp[d];
        float dx = qt.x - zt.x, dy = qt.y - zt.y;
        float dz = qt.z - zt.z, dw = qt.w - zt.w;
        float4 o;
        o.x = zt.x + dx; o.y = zt.y + dy;   // mirrors reference z + (q - z)
        o.z = zt.z + dz; o.w = zt.w + dw;
        op[d] = o;
        ss += dx*dx + dy*dy + dz*dz + dw*dw;
    }

    __shared__ float red[256];
    red[threadIdx.x] = ss;
    __syncthreads();
    #pragma unroll
    for (int s = 128; s > 0; s >>= 1) {
        if (threadIdx.x < s) red[threadIdx.x] += red[threadIdx.x + s];
        __syncthreads();
    }
    if (threadIdx.x == 0) partials[blockIdx.x] = red[0];
}

// -------- kernel D: reduce 1024 partials -> both losses --------
__global__ __launch_bounds__(256) void loss_kernel(const float* __restrict__ partials,
                                                   float* __restrict__ out) {
    __shared__ float red[256];
    red[threadIdx.x] = (partials[threadIdx.x]       + partials[threadIdx.x + 256])
                     + (partials[threadIdx.x + 512] + partials[threadIdx.x + 768]);
    __syncthreads();
    #pragma unroll
    for (int st = 128; st > 0; st >>= 1) {
        if (threadIdx.x < st) red[threadIdx.x] += red[threadIdx.x + st];
        __syncthreads();
    }
    if (threadIdx.x == 0) {
        float mean = red[0] / (float)((size_t)N_VOX * DIM);
        out[(size_t)N_VOX * DIM + 0] = mean;
        out[(size_t)N_VOX * DIM + 1] = mean;
    }
}

extern "C" void kernel_launch(void* const* d_in, const int* in_sizes, int n_in,
                              void* d_out, int out_size, void* d_ws, size_t ws_size,
                              hipStream_t stream) {
    const float* z  = (const float*)d_in[0];   // [32768, 64]
    const float* cb = (const float*)d_in[1];   // [8192, 64]
    float* out = (float*)d_out;

    // ws: stream [2 MB] | c0arr [32 KB] | cand_val [1 MB] | cand_idx [1 MB] | partials [4 KB]
    char*  bstream  = (char*)d_ws;
    float* c0arr    = (float*)(bstream + (size_t)NTILES * TILE_BYTES);
    float* cand_val = c0arr + N_EMB;
    int*   cand_idx = (int*)(cand_val + (size_t)NCHUNK * N_VOX);
    float* partials = (float*)(cand_idx + (size_t)NCHUNK * N_VOX);

    cbprep_kernel  <<<dim3(NTILES), dim3(256), 0, stream>>>(cb, bstream, c0arr);
    scan_kernel    <<<dim3((N_VOX / 256) * NCHUNK), dim3(512), 0, stream>>>(z, bstream, c0arr, cand_val, cand_idx);
    finalize_kernel<<<dim3(N_VOX * 8 / 256), dim3(256), 0, stream>>>(z, cb, cand_val, cand_idx, out, partials);
    loss_kernel    <<<1, 256, 0, stream>>>(partials, out);
}